// Round 10
// baseline (212.031 us; speedup 1.0000x reference)
//
#include <hip/hip_runtime.h>

// x [32,64,64,64] f32, emb [64,1024] f32
// N = 131072 pixels, D = 64, K = 1024
// out = [ result: 8388608 f32 ][ argmin-as-f32: 131072 ]
//
// Round 14: BARRIER-FREE main loop. Every clean config (R3-R13) landed at
// 90-110us because each of the 32 loop iterations pays an exposed
// {STAGE -> __syncthreads(vmcnt(0) drain)} latency. Fix: a K-QUARTER of
// the codebook (64KB h+l) fits in LDS whole, so stage it in ONE burst,
// ONE barrier, then 8 compute iterations with no barriers/staging at all.
//  - vq: 4096 blocks = 1024 pixel-groups x 4 K-quarters; 2 blocks/CU
//    (LDS 65KB). Writes per-quarter (bestv,bestk) to workspace.
//  - merge: 4-way min (strict <, ascending-quarter = ascending-k first-min
//    semantics, pattern correctness-proven in R12) + fp32 gather.
//  - math/scan/butterfly verbatim R9 (absmax 0.0); two-acc form from R8.
//  - __launch_bounds__(256,2): NO register squeeze (R10/R11/R12 all died
//    of forced spills). LDS is the occupancy governor here.
//  - prep: 36x256 parallel version (proven R10-R13).

using half8  = __attribute__((ext_vector_type(8))) _Float16;
using f32x16 = __attribute__((ext_vector_type(16))) float;

__global__ void prep_kernel(const float* __restrict__ emb,
                            float* __restrict__ e2,
                            _Float16* __restrict__ eTh,
                            _Float16* __restrict__ eTl) {
    const int b = blockIdx.x;
    const int t = threadIdx.x;
    if (b < 32) {
        // h/l split: c from block (uniform), k lane-contiguous -> coalesced.
        const int c = b >> 2;                 // 0..7
        const int k = (b & 3) * 256 + t;      // 0..1023
        half8 hv, lv;
#pragma unroll
        for (int j = 0; j < 8; ++j) {
            float v = emb[(c * 8 + j) * 1024 + k];
            _Float16 h = (_Float16)v;          // same split as round 1
            hv[j] = h;
            lv[j] = (_Float16)(v - (float)h);  // exact residual
        }
        *(half8*)(eTh + k * 64 + c * 8) = hv;
        *(half8*)(eTl + k * 64 + c * 8) = lv;
    } else {
        // e2: one thread per k, ascending-d fmaf chain - bit-identical
        // op sequence to the original prep.
        const int k = (b - 32) * 256 + t;
        float s = 0.f;
#pragma unroll
        for (int d = 0; d < 64; ++d) {
            float v = emb[(d << 10) + k];
            s = fmaf(v, v, s);
        }
        e2[k] = s;
    }
}

__launch_bounds__(256, 2)
__global__ void vq_kernel(const float* __restrict__ x,
                          const _Float16* __restrict__ eTh,
                          const _Float16* __restrict__ eTl,
                          const float* __restrict__ e2,
                          float* __restrict__ wbest,
                          int* __restrict__ wkid) {
    // 8 k-tiles x (h:2048 | l:2048) halfs = 64KB, + 1KB e2 slice
    __shared__ __align__(16) _Float16 sB[8][4096];
    __shared__ float se2[256];

    const int tx  = threadIdx.x;
    const int gid = blockIdx.x;
    const int q   = gid & 3;               // K-quarter (consecutive gids
    const int n0  = (gid >> 2) * 128;      //  share a pixel group -> x reuse)
    const int bb  = n0 >> 12;
    const int hw  = n0 & 4095;
    const float* xbase = x + bb * 262144 + hw;
    const int tbase = q << 3;              // first 32-k tile of this quarter

    const int lane = tx & 63;
    const int w    = tx >> 6;
    const int c    = lane & 31;    // 32x32 col / A-row
    const int hi   = lane >> 5;    // k-half selector
    const int pxb  = w << 5;       // wave's 32-pixel base

    // ---- A-fragments straight from global (identical values, R9-proven) ---
    half8 ah[4], al[4];
#pragma unroll
    for (int ch = 0; ch < 4; ++ch) {
#pragma unroll
        for (int j = 0; j < 8; ++j) {
            float v = xbase[(ch * 16 + hi * 8 + j) * 4096 + pxb + c];
            _Float16 h = (_Float16)v;
            ah[ch][j] = h;
            al[ch][j] = (_Float16)(v - (float)h);
        }
    }
    asm volatile("" ::: "memory");   // keep fragments register-resident

    // ---- swizzled LDS read offsets for B (invariant over t) ----------------
    int Dofs[4];
#pragma unroll
    for (int ch = 0; ch < 4; ++ch) {
        const int y = c * 128 + ch * 32 + hi * 16;
        Dofs[ch] = y ^ ((c & 7) << 4);
    }

    // ---- ONE staging burst: whole 64KB quarter + e2 slice, ONE barrier -----
    const int Lb = tx * 16;                        // linear byte in 4KB tile
    const int Sb = Lb ^ (((Lb >> 7) & 7) << 4);    // sigma (self-inverse)
    const char* gH = (const char*)eTh + Sb + (tbase << 12);
    const char* gL = (const char*)eTl + Sb + (tbase << 12);
#pragma unroll
    for (int it = 0; it < 8; ++it) {
        __builtin_amdgcn_global_load_lds(
            (const __attribute__((address_space(1))) unsigned int*)(gH + (it << 12)),
            (__attribute__((address_space(3))) unsigned int*)(sB[it] + (w << 9)),
            16, 0, 0);
        __builtin_amdgcn_global_load_lds(
            (const __attribute__((address_space(1))) unsigned int*)(gL + (it << 12)),
            (__attribute__((address_space(3))) unsigned int*)(sB[it] + 2048 + (w << 9)),
            16, 0, 0);
    }
    __builtin_amdgcn_global_load_lds(
        (const __attribute__((address_space(1))) unsigned int*)((const char*)e2 + (q << 10) + tx * 4),
        (__attribute__((address_space(3))) unsigned int*)((char*)se2 + (w << 8)),
        4, 0, 0);
    __syncthreads();   // the ONLY pre-loop barrier (drains the burst)

    float best[16];
    int   bestt[16];
#pragma unroll
    for (int i = 0; i < 16; ++i) { best[i] = 3.4e38f; bestt[i] = tbase; }

    // ---- barrier-free compute: 8 iters of pure LDS + MFMA ------------------
#pragma unroll 1
    for (int it = 0; it < 8; ++it) {
        const char* bbase = (const char*)sB[it];
        const float e2v = se2[(it << 5) + c];
        half8 bh_[4], bl_[4];
#pragma unroll
        for (int ch = 0; ch < 4; ++ch) {
            bh_[ch] = *(const half8*)(bbase + Dofs[ch]);
            bl_[ch] = *(const half8*)(bbase + 4096 + Dofs[ch]);
        }

        f32x16 a1 = {};
        f32x16 a2 = {};
#pragma unroll
        for (int ch = 0; ch < 4; ++ch)
            a1 = __builtin_amdgcn_mfma_f32_32x32x16_f16(al[ch], bl_[ch], a1, 0, 0, 0);
#pragma unroll
        for (int ch = 0; ch < 4; ++ch)
            a1 = __builtin_amdgcn_mfma_f32_32x32x16_f16(al[ch], bh_[ch], a1, 0, 0, 0);
#pragma unroll
        for (int ch = 0; ch < 4; ++ch)
            a2 = __builtin_amdgcn_mfma_f32_32x32x16_f16(ah[ch], bl_[ch], a2, 0, 0, 0);
#pragma unroll
        for (int ch = 0; ch < 4; ++ch)
            a2 = __builtin_amdgcn_mfma_f32_32x32x16_f16(ah[ch], bh_[ch], a2, 0, 0, 0);

        const int t = tbase + it;
#pragma unroll
        for (int r = 0; r < 16; ++r) {
            float dist = fmaf(-2.f, a1[r] + a2[r], e2v);
            if (dist < best[r]) { best[r] = dist; bestt[r] = t; }
        }
    }

    // ---- per-pixel argmin within this quarter: butterfly over 32 lanes -----
    // k = t*32 + c; ascending-t strict < kept earliest k per lane; cross-lane
    // merge breaks ties toward smaller k. C layout (verified m74/m101):
    // col = lane&31, row = (r&3) + 8*(r>>2) + 4*hi.
#pragma unroll
    for (int r = 0; r < 16; ++r) {
        float bv = best[r];
        int   bk = (bestt[r] << 5) + c;
#pragma unroll
        for (int m = 1; m < 32; m <<= 1) {
            float ov = __shfl_xor(bv, m, 64);
            int   ok = __shfl_xor(bk, m, 64);
            if (ov < bv || (ov == bv && ok < bk)) { bv = ov; bk = ok; }
        }
        if (c == 0) {
            const int row = (r & 3) + 8 * (r >> 2) + 4 * hi;
            const int pix = n0 + pxb + row;
            wbest[(q << 17) + pix] = bv;
            wkid [(q << 17) + pix] = bk;
        }
    }
}

__global__ void merge_kernel(const float* __restrict__ wbest,
                             const int* __restrict__ wkid,
                             const float* __restrict__ emb,
                             float* __restrict__ outq,
                             float* __restrict__ outidx) {
    const int tx = threadIdx.x;
    const int n0 = blockIdx.x * 256;
    const int p  = n0 + tx;                  // global pixel
    // strict <, ascending quarter: earliest quarter wins ties (its k is
    // smaller) — identical to a single ascending-k scan's first minimum.
    float bv = wbest[p];
    int   bk = wkid[p];
#pragma unroll
    for (int q = 1; q < 4; ++q) {
        float v = wbest[(q << 17) + p];
        int   k = wkid [(q << 17) + p];
        if (v < bv) { bv = v; bk = k; }
    }
    outidx[p] = (float)bk;

    const int bb = n0 >> 12;
    const int hw = (n0 & 4095) + tx;
    float* obase = outq + bb * 262144 + hw;
#pragma unroll
    for (int d = 0; d < 64; ++d)
        obase[d * 4096] = emb[d * 1024 + bk];
}

extern "C" void kernel_launch(void* const* d_in, const int* in_sizes, int n_in,
                              void* d_out, int out_size, void* d_ws, size_t ws_size,
                              hipStream_t stream) {
    const float* x   = (const float*)d_in[0];
    const float* emb = (const float*)d_in[1];
    float* outq   = (float*)d_out;
    float* outidx = outq + 8388608;            // 32*64*64*64

    float*    e2  = (float*)d_ws;                               // 4 KB
    _Float16* eTh = (_Float16*)((char*)d_ws + 4096);            // 128 KB
    _Float16* eTl = (_Float16*)((char*)d_ws + 4096 + 131072);   // 128 KB
    float*    wbest = (float*)((char*)d_ws + 266240);           // 2 MB
    int*      wkid  = (int*)((char*)d_ws + 266240 + 2097152);   // 2 MB

    prep_kernel<<<36, 256, 0, stream>>>(emb, e2, eTh, eTl);
    vq_kernel<<<4096, 256, 0, stream>>>(x, eTh, eTl, e2, wbest, wkid);
    merge_kernel<<<512, 256, 0, stream>>>(wbest, wkid, emb, outq, outidx);
}

// Round 11
// 166.164 us; speedup vs baseline: 1.2760x; 1.2760x over previous
//
#include <hip/hip_runtime.h>

// x [32,64,64,64] f32, emb [64,1024] f32
// N = 131072 pixels, D = 64, K = 1024
// out = [ result: 8388608 f32 ][ argmin-as-f32: 131072 ]
//
// Round 15: SINGLE-KERNEL FUSION of R9 (the session's proven floor:
// vq 90us, absmax 0.0, VGPR 64, zero scratch). Evidence: a ~55-70us
// non-vq cost persists in EVERY round regardless of prep speed/structure
// (R13: fast parallel prep, gap still 71us) -> it's per-kernel-boundary
// overhead, ~25-30us/launch. Kill it: zero auxiliary kernels.
//  - prep fused: each block stages raw fp32 emb (same 4B/elem as h+l f16)
//    and converts h/l on the fly: 8 coalesced loads -> 24 VALU -> 2
//    swizzled ds_write_b128 per thread per tile. LDS tile is bit-identical
//    to prep's eT output.
//  - e2 fused: per-block pre-loop, EXACT ascending-d fmaf chain per k
//    (4 k/thread, lane-coalesced reads), ~1us, into se2[1024].
//  - main loop/argmin/gather: R9 VERBATIM (same macros, same hazard
//    structure: write buf^1 while reading buf, one end barrier).

using half8  = __attribute__((ext_vector_type(8))) _Float16;
using f32x16 = __attribute__((ext_vector_type(16))) float;

__launch_bounds__(256, 4)
__global__ void vq_kernel(const float* __restrict__ x,
                          const float* __restrict__ emb,
                          float* __restrict__ outq,
                          float* __restrict__ outidx) {
    __shared__ __align__(16) _Float16 sB[2][4096];  // [buf][h:2048 | l:2048]
    __shared__ float se2[1024];
    __shared__ int samin[128];

    const int tx = threadIdx.x;
    const int n0 = blockIdx.x * 128;
    const int bb = n0 >> 12;
    const int hw = n0 & 4095;
    const float* xbase = x + bb * 262144 + hw;

    const int lane = tx & 63;
    const int w    = tx >> 6;
    const int c    = lane & 31;    // 32x32 col / A-row
    const int hi   = lane >> 5;    // k-half selector
    const int pxb  = w << 5;       // wave's 32-pixel base

    // ---- A-fragments straight from global (R9 verbatim) --------------------
    half8 ah[4], al[4];
#pragma unroll
    for (int ch = 0; ch < 4; ++ch) {
#pragma unroll
        for (int j = 0; j < 8; ++j) {
            float v = xbase[(ch * 16 + hi * 8 + j) * 4096 + pxb + c];
            _Float16 h = (_Float16)v;
            ah[ch][j] = h;
            al[ch][j] = (_Float16)(v - (float)h);
        }
    }
    asm volatile("" ::: "memory");   // keep fragments register-resident

    // ---- e2: exact ascending-d fmaf chain, 4 k's per thread ----------------
    {
        float s0 = 0.f, s1 = 0.f, s2 = 0.f, s3 = 0.f;
#pragma unroll 8
        for (int d = 0; d < 64; ++d) {
            const float* row = emb + (d << 10);
            float v0 = row[tx];       s0 = fmaf(v0, v0, s0);
            float v1 = row[tx + 256]; s1 = fmaf(v1, v1, s1);
            float v2 = row[tx + 512]; s2 = fmaf(v2, v2, s2);
            float v3 = row[tx + 768]; s3 = fmaf(v3, v3, s3);
        }
        se2[tx]       = s0;
        se2[tx + 256] = s1;
        se2[tx + 512] = s2;
        se2[tx + 768] = s3;
    }

    // ---- swizzled LDS read offsets for B (R9 verbatim) ---------------------
    int Dofs[4];
#pragma unroll
    for (int ch = 0; ch < 4; ++ch) {
        const int y = c * 128 + ch * 32 + hi * 16;
        Dofs[ch] = y ^ ((c & 7) << 4);
    }

    // ---- fused staging: thread (kl, ck) builds eT[kl][ck*8..+7] h/l --------
    // Same conversion ops as prep (cvt, sub, cvt) on the same fp32 values;
    // write offset swizzle matches the read-side Dofs formula exactly.
    const int kl = tx & 31;                       // k within tile
    const int ck = tx >> 5;                       // d-chunk 0..7
    const int wofs = (kl * 128 + ck * 16) ^ ((kl & 7) << 4);
    const float* gsrc = emb + (ck << 3) * 1024 + kl;   // + t*32 + j*1024

#define STAGEC(BUF, TT)                                                       \
    {                                                                         \
        const float* src_ = gsrc + ((TT) << 5);                               \
        float v_[8];                                                          \
        _Pragma("unroll")                                                     \
        for (int j = 0; j < 8; ++j) v_[j] = src_[j << 10];                    \
        half8 hv_, lv_;                                                       \
        _Pragma("unroll")                                                     \
        for (int j = 0; j < 8; ++j) {                                         \
            _Float16 h_ = (_Float16)v_[j];                                    \
            hv_[j] = h_;                                                      \
            lv_[j] = (_Float16)(v_[j] - (float)h_);                           \
        }                                                                     \
        *(half8*)((char*)sB[BUF] + wofs) = hv_;                               \
        *(half8*)((char*)sB[BUF] + 4096 + wofs) = lv_;                        \
    }

    float best[16];
    int   bestt[16];
#pragma unroll
    for (int i = 0; i < 16; ++i) { best[i] = 3.4e38f; bestt[i] = 0; }

    STAGEC(0, 0);
    __syncthreads();   // tile0 + se2 ready

    // ---- main loop: R9 verbatim structure ----------------------------------
#pragma unroll 1
    for (int t = 0; t < 32; ++t) {
        const int cur = t & 1;
        if (t < 31) STAGEC(cur ^ 1, t + 1);       // build next tile (other buf)

        const float e2v = se2[(t << 5) + c];
        const char* bbase = (const char*)sB[cur];
        half8 bh_[4], bl_[4];
#pragma unroll
        for (int ch = 0; ch < 4; ++ch) {
            bh_[ch] = *(const half8*)(bbase + Dofs[ch]);
            bl_[ch] = *(const half8*)(bbase + 4096 + Dofs[ch]);
        }

        f32x16 a = {};
#pragma unroll
        for (int ch = 0; ch < 4; ++ch)
            a = __builtin_amdgcn_mfma_f32_32x32x16_f16(al[ch], bl_[ch], a, 0, 0, 0);
#pragma unroll
        for (int ch = 0; ch < 4; ++ch)
            a = __builtin_amdgcn_mfma_f32_32x32x16_f16(al[ch], bh_[ch], a, 0, 0, 0);
#pragma unroll
        for (int ch = 0; ch < 4; ++ch)
            a = __builtin_amdgcn_mfma_f32_32x32x16_f16(ah[ch], bl_[ch], a, 0, 0, 0);
#pragma unroll
        for (int ch = 0; ch < 4; ++ch)
            a = __builtin_amdgcn_mfma_f32_32x32x16_f16(ah[ch], bh_[ch], a, 0, 0, 0);

#pragma unroll
        for (int r = 0; r < 16; ++r) {
            float dist = fmaf(-2.f, a[r], e2v);
            if (dist < best[r]) { best[r] = dist; bestt[r] = t; }
        }
        __syncthreads();   // this iter's reads done; next tile's writes done
    }

    // ---- per-pixel argmin: butterfly over the 32 cols (R9 verbatim) --------
    // k = t*32 + c; ascending-t strict < kept earliest k per lane; cross-lane
    // merge breaks ties toward smaller k. C layout (verified m74/m101):
    // col = lane&31, row = (r&3) + 8*(r>>2) + 4*hi.
#pragma unroll
    for (int r = 0; r < 16; ++r) {
        float bv = best[r];
        int   bk = (bestt[r] << 5) + c;
#pragma unroll
        for (int m = 1; m < 32; m <<= 1) {
            float ov = __shfl_xor(bv, m, 64);
            int   ok = __shfl_xor(bk, m, 64);
            if (ov < bv || (ov == bv && ok < bk)) { bv = ov; bk = ok; }
        }
        if (c == 0) {
            const int row = (r & 3) + 8 * (r >> 2) + 4 * hi;
            samin[pxb + row] = bk;
        }
    }
    __syncthreads();

    if (tx < 128) outidx[n0 + tx] = (float)samin[tx];

    // ---- gather exact fp32 codebook rows -> output (R9 verbatim) -----------
    const int p = tx & 127;
    const int drow = tx >> 7;                 // 0 or 1
    const int amin = samin[p];
    float* obase = outq + bb * 262144 + hw + p;
#pragma unroll
    for (int it = 0; it < 32; ++it) {
        int d = (it << 1) + drow;
        obase[d * 4096] = emb[d * 1024 + amin];
    }
}

extern "C" void kernel_launch(void* const* d_in, const int* in_sizes, int n_in,
                              void* d_out, int out_size, void* d_ws, size_t ws_size,
                              hipStream_t stream) {
    const float* x   = (const float*)d_in[0];
    const float* emb = (const float*)d_in[1];
    float* outq   = (float*)d_out;
    float* outidx = outq + 8388608;            // 32*64*64*64

    vq_kernel<<<1024, 256, 0, stream>>>(x, emb, outq, outidx);
}

// Round 12
// 154.616 us; speedup vs baseline: 1.3713x; 1.0747x over previous
//
#include <hip/hip_runtime.h>

// x [32,64,64,64] f32, emb [64,1024] f32
// N = 131072 pixels, D = 64, K = 1024
// out = [ result: 8388608 f32 ][ argmin-as-f32: 131072 ]
//
// Round 16: R9 base (proven 90us / absmax 0.0 / zero scratch) with the
// scan VALU cut 64 -> ~26 instr/iter:
//  - SWAPPED MFMA operands: mfma(eT_frag, x_frag) -> C rows = k, cols =
//    pixel. Each lane holds 16 k-scores of ONE pixel -> per-tile argmin
//    is a value-only fminf tree + 16 per-r running mins (no per-element
//    index cndmasks). R9's layout (rows=pixel) forced 4 VALU per (px,k).
//  - e2 INSIDE the MFMA: extra mfma with A=[e2h_h,e2h_l,0..] (split-f16
//    of e2/2 per k, packed u32 by prep) and B=[1,1,0..]; x-fragments
//    negated at load (exact). score = e2/2 - x.e directly from the
//    accumulator; the 16 fmaf(-2,a,e2)/iter vanish. argmin(score) ==
//    argmin(dist); ulp-level rounding changes are argmin-safe (R8
//    precedent: full summation-tree change -> absmax 0.0).
//  - index recovery: track (best, bt=tile) [2 ops/iter]; at end find r*
//    by brun[r]==best (descending r -> smallest r = smallest k), then
//    k = bt*32 + row(r*); one hi<->hi+32 exchange replaces the old
//    16x butterfly (~400 VALU saved post-loop).
//  - LDS: samin aliased into sB -> 16.4 KB total.
//  - staging/Dofs/2-phase loop/gather: R9 VERBATIM.

using half8  = __attribute__((ext_vector_type(8))) _Float16;
using f32x16 = __attribute__((ext_vector_type(16))) float;
using u32x4  = __attribute__((ext_vector_type(4))) unsigned int;

static __device__ __forceinline__ unsigned int f16bits(_Float16 h) {
    union { _Float16 f; unsigned short u; } cv; cv.f = h; return (unsigned int)cv.u;
}

__global__ void prep_kernel(const float* __restrict__ emb,
                            unsigned int* __restrict__ e2p,
                            _Float16* __restrict__ eTh,
                            _Float16* __restrict__ eTl) {
    const int b = blockIdx.x;
    const int t = threadIdx.x;
    if (b < 32) {
        // h/l split: c from block (uniform), k lane-contiguous -> coalesced.
        const int c = b >> 2;                 // 0..7
        const int k = (b & 3) * 256 + t;      // 0..1023
        half8 hv, lv;
#pragma unroll
        for (int j = 0; j < 8; ++j) {
            float v = emb[(c * 8 + j) * 1024 + k];
            _Float16 h = (_Float16)v;          // same split as round 1
            hv[j] = h;
            lv[j] = (_Float16)(v - (float)h);  // exact residual
        }
        *(half8*)(eTh + k * 64 + c * 8) = hv;
        *(half8*)(eTl + k * 64 + c * 8) = lv;
    } else {
        // e2/2 as packed split-f16: exact ascending-d fmaf chain, then
        // e2h = 0.5*s (exact scale), h/l split (same op pattern as eT).
        const int k = (b - 32) * 256 + t;
        float s = 0.f;
#pragma unroll
        for (int d = 0; d < 64; ++d) {
            float v = emb[(d << 10) + k];
            s = fmaf(v, v, s);
        }
        const float e2h = 0.5f * s;
        _Float16 h = (_Float16)e2h;
        _Float16 l = (_Float16)(e2h - (float)h);
        e2p[k] = f16bits(h) | (f16bits(l) << 16);
    }
}

__launch_bounds__(256, 4)
__global__ void vq_kernel(const float* __restrict__ x,
                          const _Float16* __restrict__ eTh,
                          const _Float16* __restrict__ eTl,
                          const unsigned int* __restrict__ e2p,
                          const float* __restrict__ emb,
                          float* __restrict__ outq,
                          float* __restrict__ outidx) {
    __shared__ __align__(16) _Float16 sB[2][4096];  // [buf][h:2048 | l:2048]
    // samin aliased into sB after the loop (post-final-barrier, safe)

    const int tx = threadIdx.x;
    const int n0 = blockIdx.x * 128;
    const int bb = n0 >> 12;
    const int hw = n0 & 4095;
    const float* xbase = x + bb * 262144 + hw;

    const int lane = tx & 63;
    const int w    = tx >> 6;
    const int c    = lane & 31;    // pixel-col within wave AND eT k-row read
    const int hi   = lane >> 5;    // k-dim half selector
    const int pxb  = w << 5;       // wave's 32-pixel base

    // ---- x fragments, NEGATED (exact sign flip of the R9-proven values) ----
    half8 xh[4], xl[4];
#pragma unroll
    for (int ch = 0; ch < 4; ++ch) {
#pragma unroll
        for (int j = 0; j < 8; ++j) {
            float v = -xbase[(ch * 16 + hi * 8 + j) * 4096 + pxb + c];
            _Float16 h = (_Float16)v;
            xh[ch][j] = h;
            xl[ch][j] = (_Float16)(v - (float)h);
        }
    }
    asm volatile("" ::: "memory");   // keep fragments register-resident

    // ---- B = ones fragment for the e2 MFMA (kdim slots 0,1 only) -----------
    half8 bones = {};
    if (hi == 0) { bones[0] = (_Float16)1.0f; bones[1] = (_Float16)1.0f; }

    // ---- swizzled LDS read offsets for eT rows (R9 verbatim) ---------------
    int Dofs[4];
#pragma unroll
    for (int ch = 0; ch < 4; ++ch) {
        const int y = c * 128 + ch * 32 + hi * 16;
        Dofs[ch] = y ^ ((c & 7) << 4);
    }

    // ---- staging source: pre-swizzled per-thread global byte offset --------
    const int Lb = tx * 16;                        // linear byte in 4KB tile
    const int Sb = Lb ^ (((Lb >> 7) & 7) << 4);    // sigma (self-inverse)
    const char* gH = (const char*)eTh + Sb;
    const char* gL = (const char*)eTl + Sb;

#define STAGE(BUF, TT)                                                        \
    {                                                                         \
        __builtin_amdgcn_global_load_lds(                                     \
            (const __attribute__((address_space(1))) unsigned int*)(gH + ((TT) << 12)), \
            (__attribute__((address_space(3))) unsigned int*)(sB[BUF] + (w << 9)),       \
            16, 0, 0);                                                        \
        __builtin_amdgcn_global_load_lds(                                     \
            (const __attribute__((address_space(1))) unsigned int*)(gL + ((TT) << 12)), \
            (__attribute__((address_space(3))) unsigned int*)(sB[BUF] + 2048 + (w << 9)),\
            16, 0, 0);                                                        \
    }

    float brun[16];
#pragma unroll
    for (int i = 0; i < 16; ++i) brun[i] = 3.4e38f;
    float best = 3.4e38f;
    int   bt   = 0;

    STAGE(0, 0);
    __syncthreads();   // drains vmcnt(0): buf0 ready

#pragma unroll 1
    for (int t = 0; t < 32; ++t) {
        const int cur = t & 1;
        if (t < 31) STAGE(cur ^ 1, t + 1);        // prefetch next tile

        // e2 fragment: lane c carries e2/2 (h|l packed) of k = t*32+c
        const unsigned int ev = e2p[(t << 5) + c];
        union { u32x4 u; half8 h; } ae2u;
        ae2u.u = (u32x4){ (hi == 0) ? ev : 0u, 0u, 0u, 0u };
        const half8 ae2 = ae2u.h;

        const char* bbase = (const char*)sB[cur];
        half8 bh_[4], bl_[4];
#pragma unroll
        for (int ch = 0; ch < 4; ++ch) {
            bh_[ch] = *(const half8*)(bbase + Dofs[ch]);
            bl_[ch] = *(const half8*)(bbase + 4096 + Dofs[ch]);
        }

        // C[k][pixel] = e2/2 + sum_d e[k][d] * (-x[p][d])   (17 MFMA)
        f32x16 a = {};
        a = __builtin_amdgcn_mfma_f32_32x32x16_f16(ae2, bones, a, 0, 0, 0);
#pragma unroll
        for (int ch = 0; ch < 4; ++ch)
            a = __builtin_amdgcn_mfma_f32_32x32x16_f16(bl_[ch], xl[ch], a, 0, 0, 0);
#pragma unroll
        for (int ch = 0; ch < 4; ++ch)
            a = __builtin_amdgcn_mfma_f32_32x32x16_f16(bl_[ch], xh[ch], a, 0, 0, 0);
#pragma unroll
        for (int ch = 0; ch < 4; ++ch)
            a = __builtin_amdgcn_mfma_f32_32x32x16_f16(bh_[ch], xl[ch], a, 0, 0, 0);
#pragma unroll
        for (int ch = 0; ch < 4; ++ch)
            a = __builtin_amdgcn_mfma_f32_32x32x16_f16(bh_[ch], xh[ch], a, 0, 0, 0);

        // ---- cheap scan: 16 per-r mins + value-only tree + (best,bt) -------
#pragma unroll
        for (int r = 0; r < 16; ++r) brun[r] = fminf(brun[r], a[r]);
        float m0 = fminf(fminf(a[0], a[1]),  fminf(a[2], a[3]));
        float m1 = fminf(fminf(a[4], a[5]),  fminf(a[6], a[7]));
        float m2 = fminf(fminf(a[8], a[9]),  fminf(a[10], a[11]));
        float m3 = fminf(fminf(a[12], a[13]), fminf(a[14], a[15]));
        float m  = fminf(fminf(m0, m1), fminf(m2, m3));
        if (m < best) bt = t;            // strict <: earliest tile on ties
        best = fminf(best, m);

        __syncthreads();   // this iter's reads done; prefetch drained
    }

    // ---- index recovery: smallest r with brun[r]==best (descending scan) ---
    int rst = 0;
#pragma unroll
    for (int rr = 15; rr >= 0; --rr)
        if (brun[rr] == best) rst = rr;
    const int row = (rst & 3) + 8 * (rst >> 2) + 4 * hi;   // k_local (m74/m101)
    int bk = (bt << 5) + row;

    // ---- hi-half exchange: the two lanes of pixel pxb+c merge (v,k) --------
    {
        float ov = __shfl_xor(best, 32, 64);
        int   ok = __shfl_xor(bk, 32, 64);
        if (ov < best || (ov == best && ok < bk)) { best = ov; bk = ok; }
    }

    int* samin = (int*)&sB[0][0];     // alias: sB reads are done (post-barrier)
    if (lane < 32) samin[pxb + c] = bk;
    __syncthreads();

    if (tx < 128) outidx[n0 + tx] = (float)samin[tx];

    // ---- gather exact fp32 codebook rows -> output (R9 verbatim) -----------
    const int p = tx & 127;
    const int drow = tx >> 7;                 // 0 or 1
    const int amin = samin[p];
    float* obase = outq + bb * 262144 + hw + p;
#pragma unroll
    for (int it = 0; it < 32; ++it) {
        int d = (it << 1) + drow;
        obase[d * 4096] = emb[d * 1024 + amin];
    }
}

extern "C" void kernel_launch(void* const* d_in, const int* in_sizes, int n_in,
                              void* d_out, int out_size, void* d_ws, size_t ws_size,
                              hipStream_t stream) {
    const float* x   = (const float*)d_in[0];
    const float* emb = (const float*)d_in[1];
    float* outq   = (float*)d_out;
    float* outidx = outq + 8388608;            // 32*64*64*64

    unsigned int* e2p = (unsigned int*)d_ws;                    // 4 KB
    _Float16*     eTh = (_Float16*)((char*)d_ws + 4096);        // 128 KB
    _Float16*     eTl = (_Float16*)((char*)d_ws + 4096 + 131072); // 128 KB

    prep_kernel<<<36, 256, 0, stream>>>(emb, e2p, eTh, eTl);
    vq_kernel<<<1024, 256, 0, stream>>>(x, eTh, eTl, e2p, emb, outq, outidx);
}